// Round 10
// baseline (619.730 us; speedup 1.0000x reference)
//
#include <hip/hip_runtime.h>
#include <hip/hip_bf16.h>
#include <stdint.h>

#define B_    2
#define N_    2048
#define DIM_  2048
#define H_    16
#define HD_   128
#define NH3   6144            // 3*H*HD
#define ROWS  4096            // B*N
#define EPS_  1e-5f

typedef unsigned short u16;
typedef __bf16 bf16x8 __attribute__((ext_vector_type(8)));
typedef float  f32x4  __attribute__((ext_vector_type(4)));

__device__ inline f32x4 mfma16(bf16x8 a, bf16x8 b, f32x4 c) {
  return __builtin_amdgcn_mfma_f32_16x16x32_bf16(a, b, c, 0, 0, 0);
}

__device__ inline u16 f2bf(float f) {
  union { float f; uint32_t u; } v; v.f = f;
  uint32_t u = v.u;
  return (u16)((u + 0x7fffu + ((u >> 16) & 1u)) >> 16);   // RNE
}
__device__ inline float bf2f(u16 u) {
  union { uint32_t u; float f; } v; v.u = ((uint32_t)u) << 16;
  return v.f;
}

__device__ inline void gload_lds16(const void* g, void* l) {
  __builtin_amdgcn_global_load_lds(
      (const __attribute__((address_space(1))) void*)g,
      (__attribute__((address_space(3))) void*)l, 16, 0, 0);
}

// ---------------- elementwise f32 -> bf16 ----------------
__global__ __launch_bounds__(256) void cvt_f32_bf16(const float* __restrict__ in,
                                                    u16* __restrict__ out, int n) {
  int i = (blockIdx.x * 256 + threadIdx.x) * 4;
  if (i >= n) return;
  float4 v = *(const float4*)&in[i];
  ushort4 o;
  o.x = f2bf(v.x); o.y = f2bf(v.y); o.z = f2bf(v.z); o.w = f2bf(v.w);
  *(ushort4*)&out[i] = o;
}

// ---------------- tiled transpose + convert: in RxC f32 -> out CxR bf16 ----------------
__global__ __launch_bounds__(256) void transpose_cvt(const float* __restrict__ in,
                                                     u16* __restrict__ out,
                                                     int R, int C) {
  __shared__ float tile[32][33];
  int tc = blockIdx.x * 32, tr = blockIdx.y * 32;
  int tx = threadIdx.x, ty = threadIdx.y;          // 32 x 8
  #pragma unroll
  for (int i = 0; i < 4; ++i)
    tile[ty + i*8][tx] = in[(size_t)(tr + ty + i*8) * C + tc + tx];
  __syncthreads();
  #pragma unroll
  for (int i = 0; i < 4; ++i)
    out[(size_t)(tc + ty + i*8) * R + tr + tx] = f2bf(tile[tx][ty + i*8]);
}

// ---------------- V transpose: qkv V-section -> vt[bh][d][n] ----------------
__global__ __launch_bounds__(256) void v_transpose(const u16* __restrict__ qkv,
                                                   u16* __restrict__ vt) {
  __shared__ u16 lT[64][130];
  int bh = blockIdx.y, n0 = blockIdx.x * 64;
  int b = bh >> 4, h = bh & 15;
  int t = threadIdx.x;
  const u16* Vb = qkv + (size_t)b * N_ * NH3 + 4096 + h * HD_;
  #pragma unroll
  for (int i = 0; i < 16; ++i) {
    int chunk = i * 256 + t;
    int n = chunk >> 6, dc = chunk & 63;
    *(ushort2*)&lT[n][dc*2] = *(const ushort2*)&Vb[(size_t)(n0+n)*NH3 + dc*2];
  }
  __syncthreads();
  u16* vo = vt + (size_t)bh * HD_ * N_;
  #pragma unroll
  for (int i = 0; i < 4; ++i) {
    int chunk = i * 256 + t;
    int d = chunk >> 3, nc = chunk & 7;
    ushort4 a, bq;
    a.x = lT[nc*8+0][d]; a.y = lT[nc*8+1][d]; a.z = lT[nc*8+2][d]; a.w = lT[nc*8+3][d];
    bq.x = lT[nc*8+4][d]; bq.y = lT[nc*8+5][d]; bq.z = lT[nc*8+6][d]; bq.w = lT[nc*8+7][d];
    u16* dst = &vo[(size_t)d * N_ + n0 + nc*8];
    *(ushort4*)dst = a;
    *(ushort4*)(dst+4) = bq;
  }
}

// ---------------- bf16 GEMM (m97 pattern + XCD swizzle), 1D grid ----------------
template <bool OUT_BF16>
__global__ __launch_bounds__(256) void gemm_bt(const u16* __restrict__ A,
                                               const u16* __restrict__ Bt,
                                               void* __restrict__ Cv,
                                               int M, int N, int K) {
  __shared__ u16 lA[128][64];
  __shared__ u16 lB[128][64];
  // XCD-aware swizzle: consecutive nid on one XCD share the Bt panel (L2-resident)
  int per = gridDim.x >> 3;
  int nid = (blockIdx.x & 7) * per + (blockIdx.x >> 3);
  int MB = M >> 7;
  int m0 = (nid % MB) * 128, n0 = (nid / MB) * 128;
  int t = threadIdx.x;
  int wave = t >> 6, lane = t & 63;
  int wr = wave >> 1, wc = wave & 1;
  int lhi = lane >> 4, llo = lane & 15;
  int lrow = lane >> 3, lcol = lane & 7;
  f32x4 acc[4][4] = {};

  for (int k0 = 0; k0 < K; k0 += 64) {
    __syncthreads();
    #pragma unroll
    for (int i = 0; i < 4; ++i) {
      int chunk = i * 4 + wave;
      int row = chunk * 8 + lrow;
      gload_lds16(&A[(size_t)(m0+row)*K + k0 + lcol*8], &lA[chunk*8][0]);
      gload_lds16(&Bt[(size_t)(n0+row)*K + k0 + lcol*8], &lB[chunk*8][0]);
    }
    __syncthreads();
    #pragma unroll
    for (int kk = 0; kk < 2; ++kk) {
      bf16x8 af[4], bfr[4];
      #pragma unroll
      for (int mi = 0; mi < 4; ++mi)
        af[mi] = *(const bf16x8*)&lA[wr*64 + mi*16 + llo][kk*32 + lhi*8];
      #pragma unroll
      for (int ni = 0; ni < 4; ++ni)
        bfr[ni] = *(const bf16x8*)&lB[wc*64 + ni*16 + llo][kk*32 + lhi*8];
      #pragma unroll
      for (int mi = 0; mi < 4; ++mi)
        #pragma unroll
        for (int ni = 0; ni < 4; ++ni)
          acc[mi][ni] = mfma16(af[mi], bfr[ni], acc[mi][ni]);
    }
  }
  #pragma unroll
  for (int mi = 0; mi < 4; ++mi)
    #pragma unroll
    for (int ni = 0; ni < 4; ++ni)
      #pragma unroll
      for (int r = 0; r < 4; ++r) {
        int row = m0 + wr*64 + mi*16 + lhi*4 + r;
        int col = n0 + wc*64 + ni*16 + llo;
        float v = acc[mi][ni][r];
        if constexpr (OUT_BF16) ((u16*)Cv)[(size_t)row*N + col] = f2bf(v);
        else                    ((float*)Cv)[(size_t)row*N + col] = v;
      }
}

// ---------------- fused RMSNorm + RoPE on q,k ----------------
__global__ __launch_bounds__(256) void norm_rope(u16* __restrict__ qkv,
                                                 const float* __restrict__ fr,
                                                 const float* __restrict__ fi,
                                                 const float* __restrict__ qw,
                                                 const float* __restrict__ kw) {
  int gw = (blockIdx.x * 256 + threadIdx.x) >> 6;
  int lane = threadIdx.x & 63;
  int row = gw >> 4, h = gw & 15;
  size_t base = (size_t)row * NH3 + h * HD_;
  ushort2 qp = *(ushort2*)&qkv[base + 2*lane];
  ushort2 kp = *(ushort2*)&qkv[base + 2048 + 2*lane];
  float q0 = bf2f(qp.x), q1 = bf2f(qp.y);
  float k0 = bf2f(kp.x), k1 = bf2f(kp.y);
  float sq = q0*q0 + q1*q1;
  float sk = k0*k0 + k1*k1;
  #pragma unroll
  for (int off = 1; off < 64; off <<= 1) {
    sq += __shfl_xor(sq, off);
    sk += __shfl_xor(sk, off);
  }
  float rq = rsqrtf(sq * (1.0f/128.0f) + EPS_);
  float rk = rsqrtf(sk * (1.0f/128.0f) + EPS_);
  float wq0 = qw[2*lane], wq1 = qw[2*lane+1];
  float wk0 = kw[2*lane], wk1 = kw[2*lane+1];
  q0 *= rq * wq0; q1 *= rq * wq1;
  k0 *= rk * wk0; k1 *= rk * wk1;
  float fre = fr[(size_t)row*64 + lane], fim = fi[(size_t)row*64 + lane];
  float qo0 = q0*fre - q1*fim, qo1 = q0*fim + q1*fre;
  float ko0 = k0*fre - k1*fim, ko1 = k0*fim + k1*fre;
  const float SC = 0.08838834764831845f;   // 1/sqrt(128) folded into q
  qo0 *= SC; qo1 *= SC;
  ushort2 qo, ko;
  qo.x = f2bf(qo0); qo.y = f2bf(qo1);
  ko.x = f2bf(ko0); ko.y = f2bf(ko1);
  *(ushort2*)&qkv[base + 2*lane] = qo;
  *(ushort2*)&qkv[base + 2048 + 2*lane] = ko;
}

// ---------------- flash attention, swapped-QK^T softmax + async-STAGE + setprio ----
// 128 q-rows/block (32/wave), KV tiles of 64. St = mfma(K,Q): lane holds 16 kv
// values of q-row (lane&15) -> in-lane softmax. T14: tile t+1 global loads issued
// into regs before computing tile t (L2 latency hides under compute); vmcnt drain
// + LDS write happen after the barrier. T5: setprio(1) around MFMA clusters.
__global__ __launch_bounds__(256) void attn(const u16* __restrict__ qkv,
                                            const u16* __restrict__ vt,
                                            u16* __restrict__ out) {
  // XCD swizzle: the 16 q-tiles of one bh stay on one XCD (K/V L2-resident)
  int nid = (blockIdx.x & 7) * 64 + (blockIdx.x >> 3);
  int bh = nid >> 4;
  int b = bh >> 4, h = bh & 15;
  int q0 = (nid & 15) * 128;
  int t = threadIdx.x, wave = t >> 6, lane = t & 63;
  int lhi = lane >> 4, llo = lane & 15;

  __shared__ u16 lK[64][136];
  __shared__ u16 lVt[128][72];
  __shared__ u16 lP[4][32][72];    // per-wave P: [q 0..31][kv 0..63]

  const u16* Qb  = qkv + (size_t)b * N_ * NH3 + h * HD_;
  const u16* Kb  = Qb + 2048;
  const u16* Vtb = vt + (size_t)bh * HD_ * N_;

  bf16x8 qf[2][4];
  #pragma unroll
  for (int pi = 0; pi < 2; ++pi) {
    const u16* qrow = Qb + (size_t)(q0 + wave*32 + pi*16 + llo) * NH3;
    #pragma unroll
    for (int kk = 0; kk < 4; ++kk)
      qf[pi][kk] = *(const bf16x8*)&qrow[kk*32 + lhi*8];
  }

  // per-thread staging addresses (constant across tiles except kv0)
  int kc_row = t >> 4, kc_col = (t & 15) * 8;        // K: 16 rows/iter-chunk of 4
  int vc_row = t >> 3, vc_col = (t & 7) * 8;         // V^T: 32 d-rows/iter-chunk of 4

  f32x4 o[2][8] = {};
  float m_own[2] = {-1e30f, -1e30f};    // running max for q = pi*16+llo (x4 replicated)
  float l_own[2] = {0.f, 0.f};

  int4 kreg[4], vreg[4];
  // prologue: issue loads for tile 0
  #pragma unroll
  for (int i = 0; i < 4; ++i)
    kreg[i] = *(const int4*)&Kb[(size_t)(i*16 + kc_row)*NH3 + kc_col];
  #pragma unroll
  for (int i = 0; i < 4; ++i)
    vreg[i] = *(const int4*)&Vtb[(size_t)(i*32 + vc_row)*N_ + vc_col];

  for (int kv0 = 0; kv0 < N_; kv0 += 64) {
    __syncthreads();                       // prev compute done reading LDS
    #pragma unroll
    for (int i = 0; i < 4; ++i)            // write staged K (vmcnt auto-inserted)
      *(int4*)&lK[i*16 + kc_row][kc_col] = kreg[i];
    #pragma unroll
    for (int i = 0; i < 4; ++i)            // write staged V^T
      *(int4*)&lVt[i*32 + vc_row][vc_col] = vreg[i];
    __syncthreads();

    if (kv0 + 64 < N_) {                   // T14: issue next tile's loads now;
      #pragma unroll                       // they fly under this tile's compute
      for (int i = 0; i < 4; ++i)
        kreg[i] = *(const int4*)&Kb[(size_t)(kv0 + 64 + i*16 + kc_row)*NH3 + kc_col];
      #pragma unroll
      for (int i = 0; i < 4; ++i)
        vreg[i] = *(const int4*)&Vtb[(size_t)(i*32 + vc_row)*N_ + kv0 + 64 + vc_col];
    }

    // St[pi][j][r] = S[kv = j*16+lhi*4+r][q = pi*16+llo]   (swapped operands)
    f32x4 St[2][4];
    #pragma unroll
    for (int pi = 0; pi < 2; ++pi)
      #pragma unroll
      for (int j = 0; j < 4; ++j) St[pi][j] = f32x4{0.f,0.f,0.f,0.f};
    __builtin_amdgcn_s_setprio(1);
    #pragma unroll
    for (int j = 0; j < 4; ++j)
      #pragma unroll
      for (int kk = 0; kk < 4; ++kk) {
        bf16x8 kf = *(const bf16x8*)&lK[j*16 + llo][kk*32 + lhi*8];
        St[0][j] = mfma16(kf, qf[0][kk], St[0][j]);
        St[1][j] = mfma16(kf, qf[1][kk], St[1][j]);
      }
    __builtin_amdgcn_s_setprio(0);

    // per-lane online softmax for own q-row, then broadcast rescale factors
    float scb[2][4];
    #pragma unroll
    for (int pi = 0; pi < 2; ++pi) {
      float mx = -1e30f;
      #pragma unroll
      for (int j = 0; j < 4; ++j) {
        float a = fmaxf(fmaxf(St[pi][j][0], St[pi][j][1]),
                        fmaxf(St[pi][j][2], St[pi][j][3]));
        mx = fmaxf(mx, a);
      }
      mx = fmaxf(mx, __shfl_xor(mx, 16));
      mx = fmaxf(mx, __shfl_xor(mx, 32));
      float mnew = fmaxf(m_own[pi], mx);
      float sc = __expf(m_own[pi] - mnew);
      m_own[pi] = mnew;
      float rs = 0.f;
      #pragma unroll
      for (int j = 0; j < 4; ++j)
        #pragma unroll
        for (int r = 0; r < 4; ++r) {
          float p = __expf(St[pi][j][r] - mnew);
          St[pi][j][r] = p;
          rs += p;
        }
      rs += __shfl_xor(rs, 16);
      rs += __shfl_xor(rs, 32);
      l_own[pi] = l_own[pi] * sc + rs;
      // lane needs sc of q-row (pi*16 + lhi*4 + r) for its o rows
      #pragma unroll
      for (int r = 0; r < 4; ++r) scb[pi][r] = __shfl(sc, lhi*4 + r, 16);
    }
    #pragma unroll
    for (int pi = 0; pi < 2; ++pi)
      #pragma unroll
      for (int d = 0; d < 8; ++d)
        #pragma unroll
        for (int r = 0; r < 4; ++r) o[pi][d][r] *= scb[pi][r];

    // P write: lane owns q=pi*16+llo, kv=j*16+lhi*4..+3 -> contiguous ds_write_b64
    #pragma unroll
    for (int pi = 0; pi < 2; ++pi)
      #pragma unroll
      for (int j = 0; j < 4; ++j) {
        union { ushort4 u; __bf16 hv[4]; } pw;
        #pragma unroll
        for (int r = 0; r < 4; ++r) pw.hv[r] = (__bf16)St[pi][j][r];
        *(ushort4*)&lP[wave][pi*16 + llo][j*16 + lhi*4] = pw.u;
      }

    // PV: O += P * V  (A = P rows q, B = V^T rows d); same-wave DS ordering
    __builtin_amdgcn_s_setprio(1);
    #pragma unroll
    for (int kk = 0; kk < 2; ++kk) {
      bf16x8 pf[2];
      #pragma unroll
      for (int pi = 0; pi < 2; ++pi)
        pf[pi] = *(const bf16x8*)&lP[wave][pi*16 + llo][kk*32 + lhi*8];
      #pragma unroll
      for (int d = 0; d < 8; ++d) {
        bf16x8 vf = *(const bf16x8*)&lVt[d*16 + llo][kk*32 + lhi*8];
        o[0][d] = mfma16(pf[0], vf, o[0][d]);
        o[1][d] = mfma16(pf[1], vf, o[1][d]);
      }
    }
    __builtin_amdgcn_s_setprio(0);
  }

  float linv[2][4];
  #pragma unroll
  for (int pi = 0; pi < 2; ++pi)
    #pragma unroll
    for (int r = 0; r < 4; ++r)
      linv[pi][r] = 1.0f / __shfl(l_own[pi], lhi*4 + r, 16);
  #pragma unroll
  for (int pi = 0; pi < 2; ++pi)
    #pragma unroll
    for (int d = 0; d < 8; ++d)
      #pragma unroll
      for (int r = 0; r < 4; ++r) {
        size_t row = (size_t)b*N_ + q0 + wave*32 + pi*16 + lhi*4 + r;
        out[row*2048 + h*HD_ + d*16 + llo] = f2bf(o[pi][d][r] * linv[pi][r]);
      }
}

extern "C" void kernel_launch(void* const* d_in, const int* in_sizes, int n_in,
                              void* d_out, int out_size, void* d_ws, size_t ws_size,
                              hipStream_t stream) {
  const float* x    = (const float*)d_in[0];
  const float* fr   = (const float*)d_in[1];
  const float* fi   = (const float*)d_in[2];
  const float* wqkv = (const float*)d_in[3];
  const float* wout = (const float*)d_in[4];
  const float* qw   = (const float*)d_in[5];
  const float* kw   = (const float*)d_in[6];
  float* out = (float*)d_out;

  char* ws = (char*)d_ws;
  const size_t SZ_XB    = (size_t)ROWS * DIM_ * 2;   // 16 MB
  const size_t SZ_WQKVT = (size_t)NH3  * DIM_ * 2;   // 24 MB
  const size_t SZ_WOUTT = (size_t)DIM_ * DIM_ * 2;   //  8 MB
  u16* xb    = (u16*)ws;
  u16* wqkvT = (u16*)(ws + SZ_XB);
  u16* woutT = (u16*)(ws + SZ_XB + SZ_WQKVT);
  u16* qkv   = (u16*)(ws + SZ_XB + SZ_WQKVT + SZ_WOUTT);
  u16* vtb   = xb;       // reuse: xb dead after GEMM1
  u16* attno = wqkvT;    // reuse: wqkvT dead after GEMM1

  cvt_f32_bf16<<<(ROWS*DIM_/4 + 255)/256, 256, 0, stream>>>(x, xb, ROWS*DIM_);
  transpose_cvt<<<dim3(NH3/32, DIM_/32), dim3(32, 8), 0, stream>>>(wqkv, wqkvT, DIM_, NH3);
  transpose_cvt<<<dim3(DIM_/32, DIM_/32), dim3(32, 8), 0, stream>>>(wout, woutT, DIM_, DIM_);
  gemm_bt<true ><<<(ROWS/128)*(NH3/128), 256, 0, stream>>>(xb, wqkvT, qkv, ROWS, NH3, DIM_);
  norm_rope<<<ROWS*H_/4, 256, 0, stream>>>(qkv, fr, fi, qw, kw);
  v_transpose<<<dim3(N_/64, B_*H_), 256, 0, stream>>>(qkv, vtb);
  attn<<<(N_/128)*(B_*H_), 256, 0, stream>>>(qkv, vtb, attno);
  gemm_bt<false><<<(ROWS/128)*(DIM_/128), 256, 0, stream>>>(attno, woutT, out, ROWS, DIM_, DIM_);
}

// Round 11
// 494.557 us; speedup vs baseline: 1.2531x; 1.2531x over previous
//
#include <hip/hip_runtime.h>
#include <hip/hip_bf16.h>
#include <stdint.h>

#define B_    2
#define N_    2048
#define DIM_  2048
#define H_    16
#define HD_   128
#define NH3   6144            // 3*H*HD
#define ROWS  4096            // B*N
#define EPS_  1e-5f

typedef unsigned short u16;
typedef __bf16 bf16x8 __attribute__((ext_vector_type(8)));
typedef float  f32x4  __attribute__((ext_vector_type(4)));

__device__ inline f32x4 mfma16(bf16x8 a, bf16x8 b, f32x4 c) {
  return __builtin_amdgcn_mfma_f32_16x16x32_bf16(a, b, c, 0, 0, 0);
}

__device__ inline u16 f2bf(float f) {
  union { float f; uint32_t u; } v; v.f = f;
  uint32_t u = v.u;
  return (u16)((u + 0x7fffu + ((u >> 16) & 1u)) >> 16);   // RNE
}
__device__ inline float bf2f(u16 u) {
  union { uint32_t u; float f; } v; v.u = ((uint32_t)u) << 16;
  return v.f;
}

__device__ inline void gload_lds16(const void* g, void* l) {
  __builtin_amdgcn_global_load_lds(
      (const __attribute__((address_space(1))) void*)g,
      (__attribute__((address_space(3))) void*)l, 16, 0, 0);
}

// ---------------- elementwise f32 -> bf16 ----------------
__global__ __launch_bounds__(256) void cvt_f32_bf16(const float* __restrict__ in,
                                                    u16* __restrict__ out, int n) {
  int i = (blockIdx.x * 256 + threadIdx.x) * 4;
  if (i >= n) return;
  float4 v = *(const float4*)&in[i];
  ushort4 o;
  o.x = f2bf(v.x); o.y = f2bf(v.y); o.z = f2bf(v.z); o.w = f2bf(v.w);
  *(ushort4*)&out[i] = o;
}

// ---------------- tiled transpose + convert: in RxC f32 -> out CxR bf16 ----------------
__global__ __launch_bounds__(256) void transpose_cvt(const float* __restrict__ in,
                                                     u16* __restrict__ out,
                                                     int R, int C) {
  __shared__ float tile[32][33];
  int tc = blockIdx.x * 32, tr = blockIdx.y * 32;
  int tx = threadIdx.x, ty = threadIdx.y;          // 32 x 8
  #pragma unroll
  for (int i = 0; i < 4; ++i)
    tile[ty + i*8][tx] = in[(size_t)(tr + ty + i*8) * C + tc + tx];
  __syncthreads();
  #pragma unroll
  for (int i = 0; i < 4; ++i)
    out[(size_t)(tc + ty + i*8) * R + tr + tx] = f2bf(tile[tx][ty + i*8]);
}

// ---------------- V transpose: qkv V-section -> vt[bh][d][n] ----------------
__global__ __launch_bounds__(256) void v_transpose(const u16* __restrict__ qkv,
                                                   u16* __restrict__ vt) {
  __shared__ u16 lT[64][130];
  int bh = blockIdx.y, n0 = blockIdx.x * 64;
  int b = bh >> 4, h = bh & 15;
  int t = threadIdx.x;
  const u16* Vb = qkv + (size_t)b * N_ * NH3 + 4096 + h * HD_;
  #pragma unroll
  for (int i = 0; i < 16; ++i) {
    int chunk = i * 256 + t;
    int n = chunk >> 6, dc = chunk & 63;
    *(ushort2*)&lT[n][dc*2] = *(const ushort2*)&Vb[(size_t)(n0+n)*NH3 + dc*2];
  }
  __syncthreads();
  u16* vo = vt + (size_t)bh * HD_ * N_;
  #pragma unroll
  for (int i = 0; i < 4; ++i) {
    int chunk = i * 256 + t;
    int d = chunk >> 3, nc = chunk & 7;
    ushort4 a, bq;
    a.x = lT[nc*8+0][d]; a.y = lT[nc*8+1][d]; a.z = lT[nc*8+2][d]; a.w = lT[nc*8+3][d];
    bq.x = lT[nc*8+4][d]; bq.y = lT[nc*8+5][d]; bq.z = lT[nc*8+6][d]; bq.w = lT[nc*8+7][d];
    u16* dst = &vo[(size_t)d * N_ + n0 + nc*8];
    *(ushort4*)dst = a;
    *(ushort4*)(dst+4) = bq;
  }
}

// ---------------- bf16 GEMM (m97 pattern + XCD swizzle), 1D grid ----------------
template <bool OUT_BF16>
__global__ __launch_bounds__(256) void gemm_bt(const u16* __restrict__ A,
                                               const u16* __restrict__ Bt,
                                               void* __restrict__ Cv,
                                               int M, int N, int K) {
  __shared__ u16 lA[128][64];
  __shared__ u16 lB[128][64];
  // XCD-aware swizzle: consecutive nid on one XCD share the Bt panel (L2-resident)
  int per = gridDim.x >> 3;
  int nid = (blockIdx.x & 7) * per + (blockIdx.x >> 3);
  int MB = M >> 7;
  int m0 = (nid % MB) * 128, n0 = (nid / MB) * 128;
  int t = threadIdx.x;
  int wave = t >> 6, lane = t & 63;
  int wr = wave >> 1, wc = wave & 1;
  int lhi = lane >> 4, llo = lane & 15;
  int lrow = lane >> 3, lcol = lane & 7;
  f32x4 acc[4][4] = {};

  for (int k0 = 0; k0 < K; k0 += 64) {
    __syncthreads();
    #pragma unroll
    for (int i = 0; i < 4; ++i) {
      int chunk = i * 4 + wave;
      int row = chunk * 8 + lrow;
      gload_lds16(&A[(size_t)(m0+row)*K + k0 + lcol*8], &lA[chunk*8][0]);
      gload_lds16(&Bt[(size_t)(n0+row)*K + k0 + lcol*8], &lB[chunk*8][0]);
    }
    __syncthreads();
    #pragma unroll
    for (int kk = 0; kk < 2; ++kk) {
      bf16x8 af[4], bfr[4];
      #pragma unroll
      for (int mi = 0; mi < 4; ++mi)
        af[mi] = *(const bf16x8*)&lA[wr*64 + mi*16 + llo][kk*32 + lhi*8];
      #pragma unroll
      for (int ni = 0; ni < 4; ++ni)
        bfr[ni] = *(const bf16x8*)&lB[wc*64 + ni*16 + llo][kk*32 + lhi*8];
      #pragma unroll
      for (int mi = 0; mi < 4; ++mi)
        #pragma unroll
        for (int ni = 0; ni < 4; ++ni)
          acc[mi][ni] = mfma16(af[mi], bfr[ni], acc[mi][ni]);
    }
  }
  #pragma unroll
  for (int mi = 0; mi < 4; ++mi)
    #pragma unroll
    for (int ni = 0; ni < 4; ++ni)
      #pragma unroll
      for (int r = 0; r < 4; ++r) {
        int row = m0 + wr*64 + mi*16 + lhi*4 + r;
        int col = n0 + wc*64 + ni*16 + llo;
        float v = acc[mi][ni][r];
        if constexpr (OUT_BF16) ((u16*)Cv)[(size_t)row*N + col] = f2bf(v);
        else                    ((float*)Cv)[(size_t)row*N + col] = v;
      }
}

// ---------------- fused RMSNorm + RoPE on q,k ----------------
__global__ __launch_bounds__(256) void norm_rope(u16* __restrict__ qkv,
                                                 const float* __restrict__ fr,
                                                 const float* __restrict__ fi,
                                                 const float* __restrict__ qw,
                                                 const float* __restrict__ kw) {
  int gw = (blockIdx.x * 256 + threadIdx.x) >> 6;
  int lane = threadIdx.x & 63;
  int row = gw >> 4, h = gw & 15;
  size_t base = (size_t)row * NH3 + h * HD_;
  ushort2 qp = *(ushort2*)&qkv[base + 2*lane];
  ushort2 kp = *(ushort2*)&qkv[base + 2048 + 2*lane];
  float q0 = bf2f(qp.x), q1 = bf2f(qp.y);
  float k0 = bf2f(kp.x), k1 = bf2f(kp.y);
  float sq = q0*q0 + q1*q1;
  float sk = k0*k0 + k1*k1;
  #pragma unroll
  for (int off = 1; off < 64; off <<= 1) {
    sq += __shfl_xor(sq, off);
    sk += __shfl_xor(sk, off);
  }
  float rq = rsqrtf(sq * (1.0f/128.0f) + EPS_);
  float rk = rsqrtf(sk * (1.0f/128.0f) + EPS_);
  float wq0 = qw[2*lane], wq1 = qw[2*lane+1];
  float wk0 = kw[2*lane], wk1 = kw[2*lane+1];
  q0 *= rq * wq0; q1 *= rq * wq1;
  k0 *= rk * wk0; k1 *= rk * wk1;
  float fre = fr[(size_t)row*64 + lane], fim = fi[(size_t)row*64 + lane];
  float qo0 = q0*fre - q1*fim, qo1 = q0*fim + q1*fre;
  float ko0 = k0*fre - k1*fim, ko1 = k0*fim + k1*fre;
  const float SC = 0.08838834764831845f;   // 1/sqrt(128) folded into q
  qo0 *= SC; qo1 *= SC;
  ushort2 qo, ko;
  qo.x = f2bf(qo0); qo.y = f2bf(qo1);
  ko.x = f2bf(ko0); ko.y = f2bf(ko1);
  *(ushort2*)&qkv[base + 2*lane] = qo;
  *(ushort2*)&qkv[base + 2048 + 2*lane] = ko;
}

// ---------------- flash attention: 8 waves/block, 16 q-rows/wave ----------------
// R9 tile structure (stage->write immediately; no cross-tile reg holding, no setprio).
// 512 threads double waves/CU (8 -> 16) for latency hiding at same LDS footprint.
__global__ __launch_bounds__(512, 4) void attn(const u16* __restrict__ qkv,
                                               const u16* __restrict__ vt,
                                               u16* __restrict__ out) {
  // XCD swizzle: the 16 q-tiles of one bh stay on one XCD (K/V L2-resident)
  int nid = (blockIdx.x & 7) * 64 + (blockIdx.x >> 3);
  int bh = nid >> 4;
  int b = bh >> 4, h = bh & 15;
  int q0 = (nid & 15) * 128;
  int t = threadIdx.x, wave = t >> 6, lane = t & 63;
  int lhi = lane >> 4, llo = lane & 15;

  __shared__ u16 lK[64][136];      // K tile [kv][d] (+8 pad)
  __shared__ u16 lVt[128][72];     // V^T tile [d][kv] (+8 pad)
  __shared__ u16 lP[8][16][72];    // per-wave P: [q 0..15][kv 0..63]

  const u16* Qb  = qkv + (size_t)b * N_ * NH3 + h * HD_;
  const u16* Kb  = Qb + 2048;
  const u16* Vtb = vt + (size_t)bh * HD_ * N_;

  bf16x8 qf[4];
  {
    const u16* qrow = Qb + (size_t)(q0 + wave*16 + llo) * NH3;
    #pragma unroll
    for (int kk = 0; kk < 4; ++kk)
      qf[kk] = *(const bf16x8*)&qrow[kk*32 + lhi*8];
  }

  f32x4 o[8] = {};
  float m_own = -1e30f;            // running max for q-row llo (x4 replicated)
  float l_own = 0.f;

  for (int kv0 = 0; kv0 < N_; kv0 += 64) {
    __syncthreads();
    #pragma unroll
    for (int i = 0; i < 2; ++i) {                 // stage K (64 x 128): 2 int4/thread
      int c = i*512 + t;
      int row = c >> 4, cc = (c & 15) * 8;
      *(int4*)&lK[row][cc] = *(const int4*)&Kb[(size_t)(kv0+row)*NH3 + cc];
    }
    #pragma unroll
    for (int i = 0; i < 2; ++i) {                 // stage V^T (128 x 64): 2 int4/thread
      int c = i*512 + t;
      int d = c >> 3, cc = (c & 7) * 8;
      *(int4*)&lVt[d][cc] = *(const int4*)&Vtb[(size_t)d*N_ + kv0 + cc];
    }
    __syncthreads();

    // St[j][r] = S[kv = j*16+lhi*4+r][q = llo]   (swapped operands)
    f32x4 St[4];
    #pragma unroll
    for (int j = 0; j < 4; ++j) St[j] = f32x4{0.f,0.f,0.f,0.f};
    #pragma unroll
    for (int j = 0; j < 4; ++j)
      #pragma unroll
      for (int kk = 0; kk < 4; ++kk) {
        bf16x8 kf = *(const bf16x8*)&lK[j*16 + llo][kk*32 + lhi*8];
        St[j] = mfma16(kf, qf[kk], St[j]);
      }

    // per-lane online softmax for own q-row (llo), reduce across lhi replicas
    float mx = -1e30f;
    #pragma unroll
    for (int j = 0; j < 4; ++j) {
      float a = fmaxf(fmaxf(St[j][0], St[j][1]), fmaxf(St[j][2], St[j][3]));
      mx = fmaxf(mx, a);
    }
    mx = fmaxf(mx, __shfl_xor(mx, 16));
    mx = fmaxf(mx, __shfl_xor(mx, 32));
    float mnew = fmaxf(m_own, mx);
    float sc = __expf(m_own - mnew);
    m_own = mnew;
    float rs = 0.f;
    #pragma unroll
    for (int j = 0; j < 4; ++j)
      #pragma unroll
      for (int r = 0; r < 4; ++r) {
        float p = __expf(St[j][r] - mnew);
        St[j][r] = p;
        rs += p;
      }
    rs += __shfl_xor(rs, 16);
    rs += __shfl_xor(rs, 32);
    l_own = l_own * sc + rs;
    float scb[4];
    #pragma unroll
    for (int r = 0; r < 4; ++r) scb[r] = __shfl(sc, lhi*4 + r, 16);
    #pragma unroll
    for (int d = 0; d < 8; ++d)
      #pragma unroll
      for (int r = 0; r < 4; ++r) o[d][r] *= scb[r];

    // P write: lane owns q=llo, kv=j*16+lhi*4..+3 -> contiguous ds_write_b64
    #pragma unroll
    for (int j = 0; j < 4; ++j) {
      union { ushort4 u; __bf16 hv[4]; } pw;
      #pragma unroll
      for (int r = 0; r < 4; ++r) pw.hv[r] = (__bf16)St[j][r];
      *(ushort4*)&lP[wave][llo][j*16 + lhi*4] = pw.u;
    }

    // PV: O += P * V  (A = P rows q, B = V^T rows d); same-wave DS ordering
    #pragma unroll
    for (int kk = 0; kk < 2; ++kk) {
      bf16x8 pf = *(const bf16x8*)&lP[wave][llo][kk*32 + lhi*8];
      #pragma unroll
      for (int d = 0; d < 8; ++d) {
        bf16x8 vf = *(const bf16x8*)&lVt[d*16 + llo][kk*32 + lhi*8];
        o[d] = mfma16(pf, vf, o[d]);
      }
    }
  }

  float linv[4];
  #pragma unroll
  for (int r = 0; r < 4; ++r)
    linv[r] = 1.0f / __shfl(l_own, lhi*4 + r, 16);
  #pragma unroll
  for (int d = 0; d < 8; ++d)
    #pragma unroll
    for (int r = 0; r < 4; ++r) {
      size_t row = (size_t)b*N_ + q0 + wave*16 + lhi*4 + r;
      out[row*2048 + h*HD_ + d*16 + llo] = f2bf(o[d][r] * linv[r]);
    }
}

extern "C" void kernel_launch(void* const* d_in, const int* in_sizes, int n_in,
                              void* d_out, int out_size, void* d_ws, size_t ws_size,
                              hipStream_t stream) {
  const float* x    = (const float*)d_in[0];
  const float* fr   = (const float*)d_in[1];
  const float* fi   = (const float*)d_in[2];
  const float* wqkv = (const float*)d_in[3];
  const float* wout = (const float*)d_in[4];
  const float* qw   = (const float*)d_in[5];
  const float* kw   = (const float*)d_in[6];
  float* out = (float*)d_out;

  char* ws = (char*)d_ws;
  const size_t SZ_XB    = (size_t)ROWS * DIM_ * 2;   // 16 MB
  const size_t SZ_WQKVT = (size_t)NH3  * DIM_ * 2;   // 24 MB
  const size_t SZ_WOUTT = (size_t)DIM_ * DIM_ * 2;   //  8 MB
  u16* xb    = (u16*)ws;
  u16* wqkvT = (u16*)(ws + SZ_XB);
  u16* woutT = (u16*)(ws + SZ_XB + SZ_WQKVT);
  u16* qkv   = (u16*)(ws + SZ_XB + SZ_WQKVT + SZ_WOUTT);
  u16* vtb   = xb;       // reuse: xb dead after GEMM1
  u16* attno = wqkvT;    // reuse: wqkvT dead after GEMM1

  cvt_f32_bf16<<<(ROWS*DIM_/4 + 255)/256, 256, 0, stream>>>(x, xb, ROWS*DIM_);
  transpose_cvt<<<dim3(NH3/32, DIM_/32), dim3(32, 8), 0, stream>>>(wqkv, wqkvT, DIM_, NH3);
  transpose_cvt<<<dim3(DIM_/32, DIM_/32), dim3(32, 8), 0, stream>>>(wout, woutT, DIM_, DIM_);
  gemm_bt<true ><<<(ROWS/128)*(NH3/128), 256, 0, stream>>>(xb, wqkvT, qkv, ROWS, NH3, DIM_);
  norm_rope<<<ROWS*H_/4, 256, 0, stream>>>(qkv, fr, fi, qw, kw);
  v_transpose<<<dim3(N_/64, B_*H_), 256, 0, stream>>>(qkv, vtb);
  attn<<<(N_/128)*(B_*H_), 512, 0, stream>>>(qkv, vtb, attno);
  gemm_bt<false><<<(ROWS/128)*(DIM_/128), 256, 0, stream>>>(attno, woutT, out, ROWS, DIM_, DIM_);
}

// Round 12
// 470.941 us; speedup vs baseline: 1.3159x; 1.0501x over previous
//
#include <hip/hip_runtime.h>
#include <hip/hip_bf16.h>
#include <stdint.h>

#define B_    2
#define N_    2048
#define DIM_  2048
#define H_    16
#define HD_   128
#define NH3   6144            // 3*H*HD
#define ROWS  4096            // B*N
#define EPS_  1e-5f

typedef unsigned short u16;
typedef __bf16 bf16x8 __attribute__((ext_vector_type(8)));
typedef float  f32x4  __attribute__((ext_vector_type(4)));

__device__ inline f32x4 mfma16(bf16x8 a, bf16x8 b, f32x4 c) {
  return __builtin_amdgcn_mfma_f32_16x16x32_bf16(a, b, c, 0, 0, 0);
}

__device__ inline u16 f2bf(float f) {
  union { float f; uint32_t u; } v; v.f = f;
  uint32_t u = v.u;
  return (u16)((u + 0x7fffu + ((u >> 16) & 1u)) >> 16);   // RNE
}
__device__ inline float bf2f(u16 u) {
  union { uint32_t u; float f; } v; v.u = ((uint32_t)u) << 16;
  return v.f;
}

__device__ inline void gload_lds16(const void* g, void* l) {
  __builtin_amdgcn_global_load_lds(
      (const __attribute__((address_space(1))) void*)g,
      (__attribute__((address_space(3))) void*)l, 16, 0, 0);
}

// ---------------- elementwise f32 -> bf16 ----------------
__global__ __launch_bounds__(256) void cvt_f32_bf16(const float* __restrict__ in,
                                                    u16* __restrict__ out, int n) {
  int i = (blockIdx.x * 256 + threadIdx.x) * 4;
  if (i >= n) return;
  float4 v = *(const float4*)&in[i];
  ushort4 o;
  o.x = f2bf(v.x); o.y = f2bf(v.y); o.z = f2bf(v.z); o.w = f2bf(v.w);
  *(ushort4*)&out[i] = o;
}

// ---------------- tiled transpose + convert: in RxC f32 -> out CxR bf16 ----------------
__global__ __launch_bounds__(256) void transpose_cvt(const float* __restrict__ in,
                                                     u16* __restrict__ out,
                                                     int R, int C) {
  __shared__ float tile[32][33];
  int tc = blockIdx.x * 32, tr = blockIdx.y * 32;
  int tx = threadIdx.x, ty = threadIdx.y;          // 32 x 8
  #pragma unroll
  for (int i = 0; i < 4; ++i)
    tile[ty + i*8][tx] = in[(size_t)(tr + ty + i*8) * C + tc + tx];
  __syncthreads();
  #pragma unroll
  for (int i = 0; i < 4; ++i)
    out[(size_t)(tc + ty + i*8) * R + tr + tx] = f2bf(tile[tx][ty + i*8]);
}

// ---------------- V transpose: qkv V-section -> vt[bh][d][n] ----------------
__global__ __launch_bounds__(256) void v_transpose(const u16* __restrict__ qkv,
                                                   u16* __restrict__ vt) {
  __shared__ u16 lT[64][130];
  int bh = blockIdx.y, n0 = blockIdx.x * 64;
  int b = bh >> 4, h = bh & 15;
  int t = threadIdx.x;
  const u16* Vb = qkv + (size_t)b * N_ * NH3 + 4096 + h * HD_;
  #pragma unroll
  for (int i = 0; i < 16; ++i) {
    int chunk = i * 256 + t;
    int n = chunk >> 6, dc = chunk & 63;
    *(ushort2*)&lT[n][dc*2] = *(const ushort2*)&Vb[(size_t)(n0+n)*NH3 + dc*2];
  }
  __syncthreads();
  u16* vo = vt + (size_t)bh * HD_ * N_;
  #pragma unroll
  for (int i = 0; i < 4; ++i) {
    int chunk = i * 256 + t;
    int d = chunk >> 3, nc = chunk & 7;
    ushort4 a, bq;
    a.x = lT[nc*8+0][d]; a.y = lT[nc*8+1][d]; a.z = lT[nc*8+2][d]; a.w = lT[nc*8+3][d];
    bq.x = lT[nc*8+4][d]; bq.y = lT[nc*8+5][d]; bq.z = lT[nc*8+6][d]; bq.w = lT[nc*8+7][d];
    u16* dst = &vo[(size_t)d * N_ + n0 + nc*8];
    *(ushort4*)dst = a;
    *(ushort4*)(dst+4) = bq;
  }
}

// ---------------- bf16 GEMM (m97 pattern + XCD swizzle + GROUP_M L2 tiling) --------
// Within each XCD's contiguous nid chunk, blocks cover an 8m x (NB-slice) rectangle
// so the per-XCD concurrent working set (~320KB/K-step) is L2-resident.
template <bool OUT_BF16>
__global__ __launch_bounds__(256) void gemm_bt(const u16* __restrict__ A,
                                               const u16* __restrict__ Bt,
                                               void* __restrict__ Cv,
                                               int M, int N, int K) {
  __shared__ u16 lA[128][64];
  __shared__ u16 lB[128][64];
  int per = gridDim.x >> 3;
  int nid = (blockIdx.x & 7) * per + (blockIdx.x >> 3);   // XCD-contiguous chunks
  int NB = N >> 7;
  const int GM = 8;                                        // group of 8 m-tiles
  int nig = GM * NB;
  int grp = nid / nig, rem = nid % nig;
  int m0 = (grp * GM + (rem % GM)) * 128;
  int n0 = (rem / GM) * 128;
  int t = threadIdx.x;
  int wave = t >> 6, lane = t & 63;
  int wr = wave >> 1, wc = wave & 1;
  int lhi = lane >> 4, llo = lane & 15;
  int lrow = lane >> 3, lcol = lane & 7;
  f32x4 acc[4][4] = {};

  for (int k0 = 0; k0 < K; k0 += 64) {
    __syncthreads();
    #pragma unroll
    for (int i = 0; i < 4; ++i) {
      int chunk = i * 4 + wave;
      int row = chunk * 8 + lrow;
      gload_lds16(&A[(size_t)(m0+row)*K + k0 + lcol*8], &lA[chunk*8][0]);
      gload_lds16(&Bt[(size_t)(n0+row)*K + k0 + lcol*8], &lB[chunk*8][0]);
    }
    __syncthreads();
    #pragma unroll
    for (int kk = 0; kk < 2; ++kk) {
      bf16x8 af[4], bfr[4];
      #pragma unroll
      for (int mi = 0; mi < 4; ++mi)
        af[mi] = *(const bf16x8*)&lA[wr*64 + mi*16 + llo][kk*32 + lhi*8];
      #pragma unroll
      for (int ni = 0; ni < 4; ++ni)
        bfr[ni] = *(const bf16x8*)&lB[wc*64 + ni*16 + llo][kk*32 + lhi*8];
      #pragma unroll
      for (int mi = 0; mi < 4; ++mi)
        #pragma unroll
        for (int ni = 0; ni < 4; ++ni)
          acc[mi][ni] = mfma16(af[mi], bfr[ni], acc[mi][ni]);
    }
  }
  #pragma unroll
  for (int mi = 0; mi < 4; ++mi)
    #pragma unroll
    for (int ni = 0; ni < 4; ++ni)
      #pragma unroll
      for (int r = 0; r < 4; ++r) {
        int row = m0 + wr*64 + mi*16 + lhi*4 + r;
        int col = n0 + wc*64 + ni*16 + llo;
        float v = acc[mi][ni][r];
        if constexpr (OUT_BF16) ((u16*)Cv)[(size_t)row*N + col] = f2bf(v);
        else                    ((float*)Cv)[(size_t)row*N + col] = v;
      }
}

// ---------------- fused RMSNorm + RoPE on q,k ----------------
__global__ __launch_bounds__(256) void norm_rope(u16* __restrict__ qkv,
                                                 const float* __restrict__ fr,
                                                 const float* __restrict__ fi,
                                                 const float* __restrict__ qw,
                                                 const float* __restrict__ kw) {
  int gw = (blockIdx.x * 256 + threadIdx.x) >> 6;
  int lane = threadIdx.x & 63;
  int row = gw >> 4, h = gw & 15;
  size_t base = (size_t)row * NH3 + h * HD_;
  ushort2 qp = *(ushort2*)&qkv[base + 2*lane];
  ushort2 kp = *(ushort2*)&qkv[base + 2048 + 2*lane];
  float q0 = bf2f(qp.x), q1 = bf2f(qp.y);
  float k0 = bf2f(kp.x), k1 = bf2f(kp.y);
  float sq = q0*q0 + q1*q1;
  float sk = k0*k0 + k1*k1;
  #pragma unroll
  for (int off = 1; off < 64; off <<= 1) {
    sq += __shfl_xor(sq, off);
    sk += __shfl_xor(sk, off);
  }
  float rq = rsqrtf(sq * (1.0f/128.0f) + EPS_);
  float rk = rsqrtf(sk * (1.0f/128.0f) + EPS_);
  float wq0 = qw[2*lane], wq1 = qw[2*lane+1];
  float wk0 = kw[2*lane], wk1 = kw[2*lane+1];
  q0 *= rq * wq0; q1 *= rq * wq1;
  k0 *= rk * wk0; k1 *= rk * wk1;
  float fre = fr[(size_t)row*64 + lane], fim = fi[(size_t)row*64 + lane];
  float qo0 = q0*fre - q1*fim, qo1 = q0*fim + q1*fre;
  float ko0 = k0*fre - k1*fim, ko1 = k0*fim + k1*fre;
  const float SC = 0.08838834764831845f;   // 1/sqrt(128) folded into q
  qo0 *= SC; qo1 *= SC;
  ushort2 qo, ko;
  qo.x = f2bf(qo0); qo.y = f2bf(qo1);
  ko.x = f2bf(ko0); ko.y = f2bf(ko1);
  *(ushort2*)&qkv[base + 2*lane] = qo;
  *(ushort2*)&qkv[base + 2048 + 2*lane] = ko;
}

// ---------------- flash attention: 8 waves/block, 16 q-rows/wave, defer-max ---------
__global__ __launch_bounds__(512, 4) void attn(const u16* __restrict__ qkv,
                                               const u16* __restrict__ vt,
                                               u16* __restrict__ out) {
  // XCD swizzle: the 16 q-tiles of one bh stay on one XCD (K/V L2-resident)
  int nid = (blockIdx.x & 7) * 64 + (blockIdx.x >> 3);
  int bh = nid >> 4;
  int b = bh >> 4, h = bh & 15;
  int q0 = (nid & 15) * 128;
  int t = threadIdx.x, wave = t >> 6, lane = t & 63;
  int lhi = lane >> 4, llo = lane & 15;

  __shared__ u16 lK[64][136];      // K tile [kv][d] (+8 pad)
  __shared__ u16 lVt[128][72];     // V^T tile [d][kv] (+8 pad)
  __shared__ u16 lP[8][16][72];    // per-wave P: [q 0..15][kv 0..63]

  const u16* Qb  = qkv + (size_t)b * N_ * NH3 + h * HD_;
  const u16* Kb  = Qb + 2048;
  const u16* Vtb = vt + (size_t)bh * HD_ * N_;

  bf16x8 qf[4];
  {
    const u16* qrow = Qb + (size_t)(q0 + wave*16 + llo) * NH3;
    #pragma unroll
    for (int kk = 0; kk < 4; ++kk)
      qf[kk] = *(const bf16x8*)&qrow[kk*32 + lhi*8];
  }

  f32x4 o[8] = {};
  float m_own = -1e30f;            // running max for q-row llo (x4 replicated)
  float l_own = 0.f;

  for (int kv0 = 0; kv0 < N_; kv0 += 64) {
    __syncthreads();
    #pragma unroll
    for (int i = 0; i < 2; ++i) {                 // stage K (64 x 128): 2 int4/thread
      int c = i*512 + t;
      int row = c >> 4, cc = (c & 15) * 8;
      *(int4*)&lK[row][cc] = *(const int4*)&Kb[(size_t)(kv0+row)*NH3 + cc];
    }
    #pragma unroll
    for (int i = 0; i < 2; ++i) {                 // stage V^T (128 x 64): 2 int4/thread
      int c = i*512 + t;
      int d = c >> 3, cc = (c & 7) * 8;
      *(int4*)&lVt[d][cc] = *(const int4*)&Vtb[(size_t)d*N_ + kv0 + cc];
    }
    __syncthreads();

    // St[j][r] = S[kv = j*16+lhi*4+r][q = llo]   (swapped operands)
    f32x4 St[4];
    #pragma unroll
    for (int j = 0; j < 4; ++j) St[j] = f32x4{0.f,0.f,0.f,0.f};
    #pragma unroll
    for (int j = 0; j < 4; ++j)
      #pragma unroll
      for (int kk = 0; kk < 4; ++kk) {
        bf16x8 kf = *(const bf16x8*)&lK[j*16 + llo][kk*32 + lhi*8];
        St[j] = mfma16(kf, qf[kk], St[j]);
      }

    // per-lane online softmax with T13 defer-max (THR=8): skip rescale unless needed
    float mx = -1e30f;
    #pragma unroll
    for (int j = 0; j < 4; ++j) {
      float a = fmaxf(fmaxf(St[j][0], St[j][1]), fmaxf(St[j][2], St[j][3]));
      mx = fmaxf(mx, a);
    }
    mx = fmaxf(mx, __shfl_xor(mx, 16));
    mx = fmaxf(mx, __shfl_xor(mx, 32));
    if (!__all(mx <= m_own + 8.0f)) {            // wave-uniform rescale decision
      float mnew = fmaxf(m_own, mx);
      float sc = __expf(m_own - mnew);
      m_own = mnew;
      l_own *= sc;
      float scb[4];
      #pragma unroll
      for (int r = 0; r < 4; ++r) scb[r] = __shfl(sc, lhi*4 + r, 16);
      #pragma unroll
      for (int d = 0; d < 8; ++d)
        #pragma unroll
        for (int r = 0; r < 4; ++r) o[d][r] *= scb[r];
    }
    float rs = 0.f;
    #pragma unroll
    for (int j = 0; j < 4; ++j)
      #pragma unroll
      for (int r = 0; r < 4; ++r) {
        float p = __expf(St[j][r] - m_own);      // bounded by e^8; bf16 rel-prec ok
        St[j][r] = p;
        rs += p;
      }
    rs += __shfl_xor(rs, 16);
    rs += __shfl_xor(rs, 32);
    l_own += rs;

    // P write: lane owns q=llo, kv=j*16+lhi*4..+3 -> contiguous ds_write_b64
    #pragma unroll
    for (int j = 0; j < 4; ++j) {
      union { ushort4 u; __bf16 hv[4]; } pw;
      #pragma unroll
      for (int r = 0; r < 4; ++r) pw.hv[r] = (__bf16)St[j][r];
      *(ushort4*)&lP[wave][llo][j*16 + lhi*4] = pw.u;
    }

    // PV: O += P * V  (A = P rows q, B = V^T rows d); same-wave DS ordering
    #pragma unroll
    for (int kk = 0; kk < 2; ++kk) {
      bf16x8 pf = *(const bf16x8*)&lP[wave][llo][kk*32 + lhi*8];
      #pragma unroll
      for (int d = 0; d < 8; ++d) {
        bf16x8 vf = *(const bf16x8*)&lVt[d*16 + llo][kk*32 + lhi*8];
        o[d] = mfma16(pf, vf, o[d]);
      }
    }
  }

  float linv[4];
  #pragma unroll
  for (int r = 0; r < 4; ++r)
    linv[r] = 1.0f / __shfl(l_own, lhi*4 + r, 16);
  #pragma unroll
  for (int d = 0; d < 8; ++d)
    #pragma unroll
    for (int r = 0; r < 4; ++r) {
      size_t row = (size_t)b*N_ + q0 + wave*16 + lhi*4 + r;
      out[row*2048 + h*HD_ + d*16 + llo] = f2bf(o[d][r] * linv[r]);
    }
}

extern "C" void kernel_launch(void* const* d_in, const int* in_sizes, int n_in,
                              void* d_out, int out_size, void* d_ws, size_t ws_size,
                              hipStream_t stream) {
  const float* x    = (const float*)d_in[0];
  const float* fr   = (const float*)d_in[1];
  const float* fi   = (const float*)d_in[2];
  const float* wqkv = (const float*)d_in[3];
  const float* wout = (const float*)d_in[4];
  const float* qw   = (const float*)d_in[5];
  const float* kw   = (const float*)d_in[6];
  float* out = (float*)d_out;

  char* ws = (char*)d_ws;
  const size_t SZ_XB    = (size_t)ROWS * DIM_ * 2;   // 16 MB
  const size_t SZ_WQKVT = (size_t)NH3  * DIM_ * 2;   // 24 MB
  const size_t SZ_WOUTT = (size_t)DIM_ * DIM_ * 2;   //  8 MB
  u16* xb    = (u16*)ws;
  u16* wqkvT = (u16*)(ws + SZ_XB);
  u16* woutT = (u16*)(ws + SZ_XB + SZ_WQKVT);
  u16* qkv   = (u16*)(ws + SZ_XB + SZ_WQKVT + SZ_WOUTT);
  u16* vtb   = xb;       // reuse: xb dead after GEMM1
  u16* attno = wqkvT;    // reuse: wqkvT dead after GEMM1

  cvt_f32_bf16<<<(ROWS*DIM_/4 + 255)/256, 256, 0, stream>>>(x, xb, ROWS*DIM_);
  transpose_cvt<<<dim3(NH3/32, DIM_/32), dim3(32, 8), 0, stream>>>(wqkv, wqkvT, DIM_, NH3);
  transpose_cvt<<<dim3(DIM_/32, DIM_/32), dim3(32, 8), 0, stream>>>(wout, woutT, DIM_, DIM_);
  gemm_bt<true ><<<(ROWS/128)*(NH3/128), 256, 0, stream>>>(xb, wqkvT, qkv, ROWS, NH3, DIM_);
  norm_rope<<<ROWS*H_/4, 256, 0, stream>>>(qkv, fr, fi, qw, kw);
  v_transpose<<<dim3(N_/64, B_*H_), 256, 0, stream>>>(qkv, vtb);
  attn<<<(N_/128)*(B_*H_), 512, 0, stream>>>(qkv, vtb, attno);
  gemm_bt<false><<<(ROWS/128)*(DIM_/128), 256, 0, stream>>>(attno, woutT, out, ROWS, DIM_, DIM_);
}